// Round 4
// baseline (116.641 us; speedup 1.0000x reference)
//
#include <hip/hip_runtime.h>
#include <math.h>

#define B 64
#define N 16384
#define MDIM 64
#define DDIM 512
#define EPSF 1e-16f

// ws float layout
#define K_OFF      0                       // B*64
#define SCAL_OFF   (B*64)                  // B*8: kn,beta,g,s0,s1,s2,gamma,pad
#define SCORE_OFF  (SCAL_OFF + B*8)        // B*N scores
#define MS_OFF     (SCORE_OFF + B*N)       // B*32*2 per-chunk (max, sumexp)
#define MXI_OFF    (MS_OFF + B*64)         // B*2 per-batch (mx, 1/sum)
#define PSUM_OFF   (MXI_OFF + B*2)         // B*32 per-chunk pow partial sums
#define INVP_OFF   (PSUM_OFF + B*32)       // B per-batch 1/(powsum+eps)
#define PART_OFF   (INVP_OFF + B)          // B*32*64 r partials

// 16-lane (DPP row) sum reduction: row_ror 8,4,2,1. All 16 lanes end with the sum.
__device__ __forceinline__ float rowsum16(float x) {
    float t;
    t = __int_as_float(__builtin_amdgcn_update_dpp(0, __float_as_int(x), 0x128, 0xF, 0xF, true)); x += t;
    t = __int_as_float(__builtin_amdgcn_update_dpp(0, __float_as_int(x), 0x124, 0xF, 0xF, true)); x += t;
    t = __int_as_float(__builtin_amdgcn_update_dpp(0, __float_as_int(x), 0x122, 0xF, 0xF, true)); x += t;
    t = __int_as_float(__builtin_amdgcn_update_dpp(0, __float_as_int(x), 0x121, 0xF, 0xF, true)); x += t;
    return x;
}

// ---------- K1: o = c@W.T + b, activations ----------
__global__ __launch_bounds__(256) void k1(const float* __restrict__ c,
                                          const float* __restrict__ W,
                                          const float* __restrict__ bias,
                                          float* __restrict__ ws) {
    int b = blockIdx.x;
    __shared__ float cs[DDIM];
    __shared__ float osh[72];
    int tid = threadIdx.x;
    for (int i = tid; i < DDIM; i += 256) cs[i] = c[b * DDIM + i];
    __syncthreads();
    int wave = tid >> 6, lane = tid & 63;
    for (int j = wave; j < MDIM + 6; j += 4) {
        const float* wr = W + (size_t)j * DDIM;
        float sum = 0.f;
        for (int d = lane; d < DDIM; d += 64) sum += cs[d] * wr[d];
        for (int off = 32; off > 0; off >>= 1) sum += __shfl_xor(sum, off);
        if (lane == 0) osh[j] = sum + bias[j];
    }
    __syncthreads();
    if (tid < 64) ws[K_OFF + b * 64 + tid] = osh[tid];
    if (wave == 0) {
        float v = osh[lane];
        float sq = v * v;
        for (int off = 32; off > 0; off >>= 1) sq += __shfl_xor(sq, off);
        if (lane == 0) {
            float kn = sqrtf(sq);
            float ob = osh[64], og = osh[65], os0 = osh[66], os1 = osh[67],
                  os2 = osh[68], ogm = osh[69];
            float beta  = fmaxf(ob, 0.f) + log1pf(expf(-fabsf(ob)));
            float g     = 1.f / (1.f + expf(-og));
            float mx    = fmaxf(os0, fmaxf(os1, os2));
            float e0 = expf(os0 - mx), e1 = expf(os1 - mx), e2 = expf(os2 - mx);
            float es = e0 + e1 + e2;
            float gamma = 1.f + fmaxf(ogm, 0.f) + log1pf(expf(-fabsf(ogm)));
            float* sc = ws + SCAL_OFF + b * 8;
            sc[0] = kn; sc[1] = beta; sc[2] = g;
            sc[3] = e0 / es; sc[4] = e1 / es; sc[5] = e2 / es;
            sc[6] = gamma;
        }
    }
}

// ---------- K2: scores + per-chunk softmax stats ----------
__global__ __launch_bounds__(256) void k2(const float* __restrict__ mem,
                                          float* __restrict__ ws) {
    int b = blockIdx.x >> 5, chunk = blockIdx.x & 31;
    __shared__ float ks[64];
    __shared__ float kb2[2];
    __shared__ float scbuf[512];
    int tid = threadIdx.x;
    if (tid < 64) ks[tid] = ws[K_OFF + b * 64 + tid];
    if (tid == 64) kb2[0] = ws[SCAL_OFF + b * 8 + 0];
    if (tid == 65) kb2[1] = ws[SCAL_OFF + b * 8 + 1];
    __syncthreads();
    float kn = kb2[0], beta = kb2[1];
    int grp = tid >> 4, ll = tid & 15;
    float k0 = ks[ll * 4], k1v = ks[ll * 4 + 1], k2v = ks[ll * 4 + 2], k3v = ks[ll * 4 + 3];
    int row0 = chunk * 512;
    #pragma unroll 8
    for (int it = 0; it < 32; ++it) {
        int lrow = it * 16 + grp;
        int row = row0 + lrow;
        float4 v = *reinterpret_cast<const float4*>(
            mem + ((size_t)b * N + row) * MDIM + ll * 4);
        float dot = v.x * k0 + v.y * k1v + v.z * k2v + v.w * k3v;
        float sq  = v.x * v.x + v.y * v.y + v.z * v.z + v.w * v.w;
        dot = rowsum16(dot);
        sq  = rowsum16(sq);
        if (ll == 0) {
            float score = beta * (dot / (kn * sqrtf(sq) + EPSF));
            ws[SCORE_OFF + (size_t)b * N + row] = score;
            scbuf[lrow] = score;
        }
    }
    __syncthreads();
    // wave 0: chunk max + sum of exp(sc - max)
    if (tid < 64) {
        float vr[8];
        float m = -1e30f;
        #pragma unroll
        for (int j = 0; j < 8; ++j) {
            vr[j] = scbuf[tid + 64 * j];
            m = fmaxf(m, vr[j]);
        }
        #pragma unroll
        for (int off = 32; off > 0; off >>= 1) m = fmaxf(m, __shfl_xor(m, off));
        float s = 0.f;
        #pragma unroll
        for (int j = 0; j < 8; ++j) s += __expf(vr[j] - m);
        #pragma unroll
        for (int off = 32; off > 0; off >>= 1) s += __shfl_xor(s, off);
        if (tid == 0) {
            ws[MS_OFF + ((size_t)b * 32 + chunk) * 2]     = m;
            ws[MS_OFF + ((size_t)b * 32 + chunk) * 2 + 1] = s;
        }
    }
}

// ---------- KC: combine 32 chunk (m,s) -> per-batch (mx, 1/sum) ----------
__global__ __launch_bounds__(64) void kc(float* __restrict__ ws) {
    int b = blockIdx.x, lane = threadIdx.x;
    float m = -1e30f, s = 0.f;
    if (lane < 32) {
        m = ws[MS_OFF + ((size_t)b * 32 + lane) * 2];
        s = ws[MS_OFF + ((size_t)b * 32 + lane) * 2 + 1];
    }
    #pragma unroll
    for (int off = 32; off > 0; off >>= 1) {
        float m2 = __shfl_xor(m, off), s2 = __shfl_xor(s, off);
        float M = fmaxf(m, m2);
        s = s * __expf(m - M) + s2 * __expf(m2 - M);
        m = M;
    }
    if (lane == 0) {
        ws[MXI_OFF + b * 2]     = m;
        ws[MXI_OFF + b * 2 + 1] = 1.f / s;
    }
}

// ---------- KWB: w_g, shift, pow at full width; w_pow -> w_out region ----------
__global__ __launch_bounds__(256) void kwb(const float* __restrict__ w_prev,
                                           float* __restrict__ ws,
                                           float* __restrict__ w_out) {
    int b = blockIdx.x >> 5, chunk = blockIdx.x & 31;
    int tid = threadIdx.x, wave = tid >> 6, lane = tid & 63;
    __shared__ float wgL[514];   // w_g for rows [row0-1 .. row0+512]
    __shared__ float red[4];
    const float* sl = ws + SCAL_OFF + b * 8;
    float g = sl[2], s0 = sl[3], s1 = sl[4], s2 = sl[5], gamma = sl[6];
    float mx  = ws[MXI_OFF + b * 2];
    float inv = ws[MXI_OFF + b * 2 + 1];
    const float* sc = ws + SCORE_OFF + (size_t)b * N;
    const float* wp = w_prev + (size_t)b * N;
    int row0 = chunk * 512;

    // w_g(row) = g * softmax + (1-g) * w_prev
    {
        int r0 = row0 + tid;
        wgL[tid + 1]   = g * (__expf(sc[r0] - mx) * inv) + (1.f - g) * wp[r0];
        int r1 = row0 + tid + 256;
        wgL[tid + 257] = g * (__expf(sc[r1] - mx) * inv) + (1.f - g) * wp[r1];
        if (tid == 0) {
            int rl = (row0 - 1) & (N - 1);
            wgL[0] = g * (__expf(sc[rl] - mx) * inv) + (1.f - g) * wp[rl];
        }
        if (tid == 255) {
            int rr = (row0 + 512) & (N - 1);
            wgL[513] = g * (__expf(sc[rr] - mx) * inv) + (1.f - g) * wp[rr];
        }
    }
    __syncthreads();

    float wt0 = s0 * wgL[tid]       + s1 * wgL[tid + 1]   + s2 * wgL[tid + 2];
    float wt1 = s0 * wgL[tid + 256] + s1 * wgL[tid + 257] + s2 * wgL[tid + 258];
    float p0 = __expf(gamma * __logf(wt0));   // wt in (0,1]; 0 -> 0 correctly
    float p1 = __expf(gamma * __logf(wt1));
    float* wo = w_out + (size_t)b * N + row0;
    wo[tid]       = p0;
    wo[tid + 256] = p1;

    float sp = p0 + p1;
    #pragma unroll
    for (int off = 32; off > 0; off >>= 1) sp += __shfl_xor(sp, off);
    if (lane == 0) red[wave] = sp;
    __syncthreads();
    if (tid == 0)
        ws[PSUM_OFF + b * 32 + chunk] = red[0] + red[1] + red[2] + red[3];
}

// ---------- KPP: per-batch 1/(sum w_pow + eps) ----------
__global__ __launch_bounds__(64) void kpp(float* __restrict__ ws) {
    int b = blockIdx.x, lane = threadIdx.x;
    float s = (lane < 32) ? ws[PSUM_OFF + b * 32 + lane] : 0.f;
    #pragma unroll
    for (int off = 32; off > 0; off >>= 1) s += __shfl_xor(s, off);
    if (lane == 0) ws[INVP_OFF + b] = 1.f / (s + EPSF);
}

// ---------- KR: r partials from w_pow; finalize w_out = w_pow * invp ----------
__global__ __launch_bounds__(256) void kr(const float* __restrict__ mem,
                                          float* __restrict__ w_out,
                                          const float* __restrict__ ws,
                                          float* __restrict__ part) {
    int b = blockIdx.x >> 5, chunk = blockIdx.x & 31;
    int tid = threadIdx.x, grp = tid >> 4, ll = tid & 15;
    float invp = ws[INVP_OFF + b];
    float* wpow = w_out + (size_t)b * N;   // holds w_pow from kwb
    float4 acc = make_float4(0.f, 0.f, 0.f, 0.f);
    int row0 = chunk * 512;
    #pragma unroll 8
    for (int it = 0; it < 32; ++it) {
        int row = row0 + it * 16 + grp;
        float wv = wpow[row];
        float4 v = *reinterpret_cast<const float4*>(
            mem + ((size_t)b * N + row) * MDIM + ll * 4);
        acc.x += wv * v.x; acc.y += wv * v.y; acc.z += wv * v.z; acc.w += wv * v.w;
    }
    __shared__ float lds[16][64];
    lds[grp][ll * 4 + 0] = acc.x * invp;
    lds[grp][ll * 4 + 1] = acc.y * invp;
    lds[grp][ll * 4 + 2] = acc.z * invp;
    lds[grp][ll * 4 + 3] = acc.w * invp;
    __syncthreads();
    // all reads of this chunk's w_pow are done -> rescale in place to final w
    {
        float a0 = wpow[row0 + tid] * invp;
        float a1 = wpow[row0 + tid + 256] * invp;
        wpow[row0 + tid]       = a0;
        wpow[row0 + tid + 256] = a1;
    }
    if (tid < 64) {
        float sacc = 0.f;
        #pragma unroll
        for (int gi = 0; gi < 16; ++gi) sacc += lds[gi][tid];
        part[(size_t)blockIdx.x * 64 + tid] = sacc;
    }
}

// ---------- KRR: reduce partials -> r ----------
__global__ __launch_bounds__(64) void krr(const float* __restrict__ part,
                                          float* __restrict__ r) {
    int b = blockIdx.x, m = threadIdx.x;
    float s = 0.f;
    #pragma unroll
    for (int c = 0; c < 32; ++c) s += part[((size_t)b * 32 + c) * 64 + m];
    r[b * 64 + m] = s;
}

extern "C" void kernel_launch(void* const* d_in, const int* in_sizes, int n_in,
                              void* d_out, int out_size, void* d_ws, size_t ws_size,
                              hipStream_t stream) {
    const float* c      = (const float*)d_in[0];
    const float* w_prev = (const float*)d_in[1];
    const float* mem    = (const float*)d_in[2];
    const float* W      = (const float*)d_in[3];
    const float* bias   = (const float*)d_in[4];
    float* out = (float*)d_out;
    float* r_out = out;                 // B*M
    float* w_out = out + B * MDIM;      // B*N (staged as w_pow, finalized by kr)
    float* ws = (float*)d_ws;

    k1 <<<B,      256, 0, stream>>>(c, W, bias, ws);
    k2 <<<B * 32, 256, 0, stream>>>(mem, ws);
    kc <<<B,       64, 0, stream>>>(ws);
    kwb<<<B * 32, 256, 0, stream>>>(w_prev, ws, w_out);
    kpp<<<B,       64, 0, stream>>>(ws);
    kr <<<B * 32, 256, 0, stream>>>(mem, w_out, ws, ws + PART_OFF);
    krr<<<B,       64, 0, stream>>>(ws + PART_OFF, r_out);
}

// Round 5
// 111.894 us; speedup vs baseline: 1.0424x; 1.0424x over previous
//
#include <hip/hip_runtime.h>
#include <math.h>

#define B 64
#define N 16384
#define MDIM 64
#define DDIM 512
#define EPSF 1e-16f

// ws float layout
#define K_OFF      0                       // B*64
#define SCAL_OFF   (B*64)                  // B*8: kn,beta,g,s0,s1,s2,gamma,pad
#define SCORE_OFF  (SCAL_OFF + B*8)        // B*N scores
#define MS_OFF     (SCORE_OFF + B*N)       // B*32*2 per-chunk (max, sumexp)
#define MXI_OFF    (MS_OFF + B*64)         // B*2 per-batch (mx, 1/sum)
#define PSUM_OFF   (MXI_OFF + B*2)         // B*32 per-chunk pow partial sums
#define INVP_OFF   (PSUM_OFF + B*32)       // B per-batch 1/(powsum+eps)
#define PART_OFF   (INVP_OFF + B)          // B*32*64 r partials (unnormalized)

// 16-lane (DPP row) sum reduction: row_ror 8,4,2,1. All 16 lanes end with the sum.
__device__ __forceinline__ float rowsum16(float x) {
    float t;
    t = __int_as_float(__builtin_amdgcn_update_dpp(0, __float_as_int(x), 0x128, 0xF, 0xF, true)); x += t;
    t = __int_as_float(__builtin_amdgcn_update_dpp(0, __float_as_int(x), 0x124, 0xF, 0xF, true)); x += t;
    t = __int_as_float(__builtin_amdgcn_update_dpp(0, __float_as_int(x), 0x122, 0xF, 0xF, true)); x += t;
    t = __int_as_float(__builtin_amdgcn_update_dpp(0, __float_as_int(x), 0x121, 0xF, 0xF, true)); x += t;
    return x;
}

// ---------- K1: o = c@W.T + b, activations ----------
__global__ __launch_bounds__(256) void k1(const float* __restrict__ c,
                                          const float* __restrict__ W,
                                          const float* __restrict__ bias,
                                          float* __restrict__ ws) {
    int b = blockIdx.x;
    __shared__ float cs[DDIM];
    __shared__ float osh[72];
    int tid = threadIdx.x;
    for (int i = tid; i < DDIM; i += 256) cs[i] = c[b * DDIM + i];
    __syncthreads();
    int wave = tid >> 6, lane = tid & 63;
    for (int j = wave; j < MDIM + 6; j += 4) {
        const float* wr = W + (size_t)j * DDIM;
        float sum = 0.f;
        for (int d = lane; d < DDIM; d += 64) sum += cs[d] * wr[d];
        for (int off = 32; off > 0; off >>= 1) sum += __shfl_xor(sum, off);
        if (lane == 0) osh[j] = sum + bias[j];
    }
    __syncthreads();
    if (tid < 64) ws[K_OFF + b * 64 + tid] = osh[tid];
    if (wave == 0) {
        float v = osh[lane];
        float sq = v * v;
        for (int off = 32; off > 0; off >>= 1) sq += __shfl_xor(sq, off);
        if (lane == 0) {
            float kn = sqrtf(sq);
            float ob = osh[64], og = osh[65], os0 = osh[66], os1 = osh[67],
                  os2 = osh[68], ogm = osh[69];
            float beta  = fmaxf(ob, 0.f) + log1pf(expf(-fabsf(ob)));
            float g     = 1.f / (1.f + expf(-og));
            float mx    = fmaxf(os0, fmaxf(os1, os2));
            float e0 = expf(os0 - mx), e1 = expf(os1 - mx), e2 = expf(os2 - mx);
            float es = e0 + e1 + e2;
            float gamma = 1.f + fmaxf(ogm, 0.f) + log1pf(expf(-fabsf(ogm)));
            float* sc = ws + SCAL_OFF + b * 8;
            sc[0] = kn; sc[1] = beta; sc[2] = g;
            sc[3] = e0 / es; sc[4] = e1 / es; sc[5] = e2 / es;
            sc[6] = gamma;
        }
    }
}

// ---------- K2: scores + per-chunk softmax stats ----------
__global__ __launch_bounds__(256) void k2(const float* __restrict__ mem,
                                          float* __restrict__ ws) {
    int b = blockIdx.x >> 5, chunk = blockIdx.x & 31;
    __shared__ float ks[64];
    __shared__ float kb2[2];
    __shared__ float scbuf[512];
    int tid = threadIdx.x;
    if (tid < 64) ks[tid] = ws[K_OFF + b * 64 + tid];
    if (tid == 64) kb2[0] = ws[SCAL_OFF + b * 8 + 0];
    if (tid == 65) kb2[1] = ws[SCAL_OFF + b * 8 + 1];
    __syncthreads();
    float kn = kb2[0], beta = kb2[1];
    int grp = tid >> 4, ll = tid & 15;
    float k0 = ks[ll * 4], k1v = ks[ll * 4 + 1], k2v = ks[ll * 4 + 2], k3v = ks[ll * 4 + 3];
    int row0 = chunk * 512;
    #pragma unroll 8
    for (int it = 0; it < 32; ++it) {
        int lrow = it * 16 + grp;
        int row = row0 + lrow;
        float4 v = *reinterpret_cast<const float4*>(
            mem + ((size_t)b * N + row) * MDIM + ll * 4);
        float dot = v.x * k0 + v.y * k1v + v.z * k2v + v.w * k3v;
        float sq  = v.x * v.x + v.y * v.y + v.z * v.z + v.w * v.w;
        dot = rowsum16(dot);
        sq  = rowsum16(sq);
        if (ll == 0) {
            float score = beta * (dot / (kn * sqrtf(sq) + EPSF));
            ws[SCORE_OFF + (size_t)b * N + row] = score;
            scbuf[lrow] = score;
        }
    }
    __syncthreads();
    // wave 0: chunk max + sum of exp(sc - max)
    if (tid < 64) {
        float vr[8];
        float m = -1e30f;
        #pragma unroll
        for (int j = 0; j < 8; ++j) {
            vr[j] = scbuf[tid + 64 * j];
            m = fmaxf(m, vr[j]);
        }
        #pragma unroll
        for (int off = 32; off > 0; off >>= 1) m = fmaxf(m, __shfl_xor(m, off));
        float s = 0.f;
        #pragma unroll
        for (int j = 0; j < 8; ++j) s += __expf(vr[j] - m);
        #pragma unroll
        for (int off = 32; off > 0; off >>= 1) s += __shfl_xor(s, off);
        if (tid == 0) {
            ws[MS_OFF + ((size_t)b * 32 + chunk) * 2]     = m;
            ws[MS_OFF + ((size_t)b * 32 + chunk) * 2 + 1] = s;
        }
    }
}

// ---------- KC: combine 32 chunk (m,s) -> per-batch (mx, 1/sum) ----------
__global__ __launch_bounds__(64) void kc(float* __restrict__ ws) {
    int b = blockIdx.x, lane = threadIdx.x;
    float m = -1e30f, s = 0.f;
    if (lane < 32) {
        m = ws[MS_OFF + ((size_t)b * 32 + lane) * 2];
        s = ws[MS_OFF + ((size_t)b * 32 + lane) * 2 + 1];
    }
    #pragma unroll
    for (int off = 32; off > 0; off >>= 1) {
        float m2 = __shfl_xor(m, off), s2 = __shfl_xor(s, off);
        float M = fmaxf(m, m2);
        s = s * __expf(m - M) + s2 * __expf(m2 - M);
        m = M;
    }
    if (lane == 0) {
        ws[MXI_OFF + b * 2]     = m;
        ws[MXI_OFF + b * 2 + 1] = 1.f / s;
    }
}

// ---------- KRW: fused w_g/shift/pow + r-partial memory pass ----------
__global__ __launch_bounds__(256) void krw(const float* __restrict__ mem,
                                           const float* __restrict__ w_prev,
                                           float* __restrict__ ws,
                                           float* __restrict__ w_out,
                                           float* __restrict__ part) {
    int b = blockIdx.x >> 5, chunk = blockIdx.x & 31;
    int tid = threadIdx.x, wave = tid >> 6, lane = tid & 63;
    __shared__ float wgL[514];      // w_g halo buffer
    __shared__ float wpl[512];      // w_pow for this chunk (unnormalized)
    __shared__ float lds[16][64];   // r partial reduce
    __shared__ float red[4];
    const float* sl = ws + SCAL_OFF + b * 8;
    float g = sl[2], s0 = sl[3], s1 = sl[4], s2 = sl[5], gamma = sl[6];
    float mx  = ws[MXI_OFF + b * 2];
    float inv = ws[MXI_OFF + b * 2 + 1];
    const float* sc = ws + SCORE_OFF + (size_t)b * N;
    const float* wp = w_prev + (size_t)b * N;
    int row0 = chunk * 512;

    // w_g(row) = g * softmax + (1-g) * w_prev, rows row0-1 .. row0+512
    {
        int r0 = row0 + tid;
        wgL[tid + 1]   = g * (__expf(sc[r0] - mx) * inv) + (1.f - g) * wp[r0];
        int r1 = row0 + tid + 256;
        wgL[tid + 257] = g * (__expf(sc[r1] - mx) * inv) + (1.f - g) * wp[r1];
        if (tid == 0) {
            int rl = (row0 - 1) & (N - 1);
            wgL[0] = g * (__expf(sc[rl] - mx) * inv) + (1.f - g) * wp[rl];
        }
        if (tid == 255) {
            int rr = (row0 + 512) & (N - 1);
            wgL[513] = g * (__expf(sc[rr] - mx) * inv) + (1.f - g) * wp[rr];
        }
    }
    __syncthreads();

    // shift + pow; stage w_pow in LDS and to w_out (unnormalized)
    float wt0 = s0 * wgL[tid]       + s1 * wgL[tid + 1]   + s2 * wgL[tid + 2];
    float wt1 = s0 * wgL[tid + 256] + s1 * wgL[tid + 257] + s2 * wgL[tid + 258];
    float p0 = __expf(gamma * __logf(wt0));   // wt in (0,1]; ->0 correctly
    float p1 = __expf(gamma * __logf(wt1));
    wpl[tid] = p0;
    wpl[tid + 256] = p1;
    float* wo = w_out + (size_t)b * N + row0;
    wo[tid]       = p0;
    wo[tid + 256] = p1;

    // per-chunk pow-sum
    float sp = p0 + p1;
    #pragma unroll
    for (int off = 32; off > 0; off >>= 1) sp += __shfl_xor(sp, off);
    if (lane == 0) red[wave] = sp;
    __syncthreads();
    if (tid == 0)
        ws[PSUM_OFF + b * 32 + chunk] = red[0] + red[1] + red[2] + red[3];

    // memory pass: r partial with unnormalized w_pow from LDS
    int grp = tid >> 4, ll = tid & 15;
    float4 acc = make_float4(0.f, 0.f, 0.f, 0.f);
    #pragma unroll 8
    for (int it = 0; it < 32; ++it) {
        int lrow = it * 16 + grp;
        float wv = wpl[lrow];
        float4 v = *reinterpret_cast<const float4*>(
            mem + ((size_t)b * N + row0 + lrow) * MDIM + ll * 4);
        acc.x += wv * v.x; acc.y += wv * v.y; acc.z += wv * v.z; acc.w += wv * v.w;
    }
    lds[grp][ll * 4 + 0] = acc.x;
    lds[grp][ll * 4 + 1] = acc.y;
    lds[grp][ll * 4 + 2] = acc.z;
    lds[grp][ll * 4 + 3] = acc.w;
    __syncthreads();
    if (tid < 64) {
        float sacc = 0.f;
        #pragma unroll
        for (int gi = 0; gi < 16; ++gi) sacc += lds[gi][tid];
        part[(size_t)blockIdx.x * 64 + tid] = sacc;
    }
}

// ---------- KRR: total powsum -> invp; reduce partials -> r ----------
__global__ __launch_bounds__(64) void krr(const float* __restrict__ part,
                                          float* __restrict__ ws,
                                          float* __restrict__ r) {
    int b = blockIdx.x, tid = threadIdx.x;
    float s = (tid < 32) ? ws[PSUM_OFF + b * 32 + tid] : 0.f;
    #pragma unroll
    for (int off = 32; off > 0; off >>= 1) s += __shfl_xor(s, off);
    float invp = 1.f / (s + EPSF);
    if (tid == 0) ws[INVP_OFF + b] = invp;
    float srr = 0.f;
    #pragma unroll
    for (int c = 0; c < 32; ++c) srr += part[((size_t)b * 32 + c) * 64 + tid];
    r[b * 64 + tid] = srr * invp;
}

// ---------- KWF: finalize w = w_pow * invp (in place) ----------
__global__ __launch_bounds__(256) void kwf(const float* __restrict__ ws,
                                           float* __restrict__ w_out) {
    int b = blockIdx.x >> 5, chunk = blockIdx.x & 31;
    int tid = threadIdx.x;
    float invp = ws[INVP_OFF + b];
    size_t base = (size_t)b * N + chunk * 512;
    w_out[base + tid]       *= invp;
    w_out[base + tid + 256] *= invp;
}

extern "C" void kernel_launch(void* const* d_in, const int* in_sizes, int n_in,
                              void* d_out, int out_size, void* d_ws, size_t ws_size,
                              hipStream_t stream) {
    const float* c      = (const float*)d_in[0];
    const float* w_prev = (const float*)d_in[1];
    const float* mem    = (const float*)d_in[2];
    const float* W      = (const float*)d_in[3];
    const float* bias   = (const float*)d_in[4];
    float* out = (float*)d_out;
    float* r_out = out;                 // B*M
    float* w_out = out + B * MDIM;      // B*N (staged as w_pow, finalized by kwf)
    float* ws = (float*)d_ws;

    k1 <<<B,      256, 0, stream>>>(c, W, bias, ws);
    k2 <<<B * 32, 256, 0, stream>>>(mem, ws);
    kc <<<B,       64, 0, stream>>>(ws);
    krw<<<B * 32, 256, 0, stream>>>(mem, w_prev, ws, w_out, ws + PART_OFF);
    krr<<<B,       64, 0, stream>>>(ws + PART_OFF, ws, r_out);
    kwf<<<B * 32, 256, 0, stream>>>(ws, w_out);
}